// Round 8
// baseline (228.394 us; speedup 1.0000x reference)
//
#include <hip/hip_runtime.h>
#include <hip/hip_bf16.h>
#include <math.h>

#define CC  128
#define RLD 136            // halves stride for [64][128] bf16 LDS tiles (272B)
#define VLD 72             // halves stride for vT / P buffers (144B)

typedef __attribute__((ext_vector_type(8))) short bf16x8;
typedef __attribute__((ext_vector_type(4))) float f32x4;

#define MFMA16(a, b, c) __builtin_amdgcn_mfma_f32_16x16x32_bf16((a), (b), (c), 0, 0, 0)

__device__ __forceinline__ unsigned short f2bf(float f) {
    unsigned int u = __float_as_uint(f);
    u += 0x7FFFu + ((u >> 16) & 1u);
    return (unsigned short)(u >> 16);
}
__device__ __forceinline__ float bf2f(unsigned short h) {
    return __uint_as_float(((unsigned int)h) << 16);
}
// pair convert -> v_cvt_pk_bf16_f32
__device__ __forceinline__ unsigned int f2bf2u(float lo, float hi) {
    __hip_bfloat162 h = __float22bfloat162_rn(make_float2(lo, hi));
    union { __hip_bfloat162 h2; unsigned int u; } cv; cv.h2 = h;
    return cv.u;
}
__device__ __forceinline__ bf16x8 mk_bf16x8(unsigned int a0, unsigned int a1,
                                            unsigned int a2, unsigned int a3) {
    union { uint4 u; bf16x8 b; } cv;
    cv.u = make_uint4(a0, a1, a2, a3);
    return cv.b;
}
// branch-free gelu: Phi via Abramowitz-Stegun 26.2.17 (|err| < 7.5e-8)
__device__ __forceinline__ float gelu_fast(float v) {
    float ax  = fabsf(v);
    float t   = __builtin_amdgcn_rcpf(fmaf(0.2316419f, ax, 1.0f));
    float phi = 0.39894228f * __expf(-0.5f * ax * ax);
    float p   = t * fmaf(t, fmaf(t, fmaf(t, fmaf(t, 1.330274429f, -1.821255978f),
                                   1.781477937f), -0.356563782f), 0.319381530f);
    float cpos = fmaf(-phi, p, 1.0f);          // Phi(|v|)
    float c    = (v >= 0.f) ? cpos : 1.0f - cpos;
    return v * c;
}

// ---- weight pre-pack: fragment-major bf16 (scale folded in) ----
__global__ void pack_w(const float* __restrict__ src, unsigned short* __restrict__ dst,
                       int K, int N, int mode, float scale) {
    int i = blockIdx.x * 256 + threadIdx.x;
    if (i >= K * N) return;
    int j   = i & 7;
    int l   = (i >> 3) & 63;
    int tkt = i >> 9;
    int KT  = K >> 5;
    int nt  = tkt / KT;
    int kt  = tkt - nt * KT;
    int k   = kt * 32 + (l >> 4) * 8 + j;
    int n   = nt * 16 + (l & 15);
    float v = (mode == 0) ? src[k * N + n]
                          : src[(n >> 4) * (K * 16) + k * 16 + (n & 15)];
    dst[i] = f2bf(v * scale);
}

// packed-weight half offsets in d_ws
#define OQ  0
#define OKk 16384
#define OV  32768
#define OP  49152
#define O1  65536
#define O2  131072

// One block = 1 batch element (64 rows). 512 threads = 8 waves.
// 3 LDS buffers = 54,272 B -> 3 blocks/CU (6 waves/SIMD).
__global__ __launch_bounds__(512, 6) void block_fused(
    const float* __restrict__ x,
    const unsigned short* __restrict__ wpk,
    const float* __restrict__ bp,
    const float* __restrict__ b1, const float* __restrict__ b2,
    const float* __restrict__ g1, const float* __restrict__ be1,
    const float* __restrict__ g2, const float* __restrict__ be2,
    float* __restrict__ out)
{
    __shared__ __align__(16) unsigned short A [9216];  // h -> P tiles -> h2 -> f1(odd)
    __shared__ __align__(16) unsigned short Ck[8704];  // k -> attn concat -> f1(even)
    __shared__ __align__(16) unsigned short Vv[9216];  // vT -> x2

    const int tid  = threadIdx.x;
    const int lane = tid & 63;
    const int wave = tid >> 6;
    const int l15  = lane & 15;
    const int lg   = lane >> 4;

    const float* xb = x   + (size_t)blockIdx.x * (64 * CC);
    float*       ob = out + (size_t)blockIdx.x * (64 * CC);

    // ---------------- LN1: x -> A (h, bf16); one-pass E[x^2] form ----------------
    {
        float ga = g1[lane], gb = g1[lane + 64], ba = be1[lane], bb = be1[lane + 64];
        #pragma unroll 2
        for (int r = wave * 8; r < wave * 8 + 8; ++r) {
            float v0 = xb[r * CC + lane], v1 = xb[r * CC + lane + 64];
            float s = v0 + v1;
            float q = fmaf(v0, v0, v1 * v1);
            #pragma unroll
            for (int off = 32; off; off >>= 1) {
                s += __shfl_xor(s, off);
                q += __shfl_xor(q, off);
            }
            float mean = s * (1.0f / CC);
            float var  = fmaf(-mean, mean, q * (1.0f / CC));
            float rstd = __builtin_amdgcn_rsqf(var + 1e-5f);
            float d0 = v0 - mean, d1 = v1 - mean;
            unsigned int u = f2bf2u(fmaf(ga, d0 * rstd, ba), fmaf(gb, d1 * rstd, bb));
            A[r * RLD + lane]      = (unsigned short)u;
            A[r * RLD + lane + 64] = (unsigned short)(u >> 16);
        }
    }
    __syncthreads();

    const int rt  = wave >> 1;          // GEMM-phase row tile (proj/FF)
    const int cg  = wave & 1;           // GEMM-phase column group
    const int row0 = rt * 16 + lg * 4;

    // ---------------- QKV ----------------
    // (a) q^T for THIS wave's head: q^T = Wq^T @ h^T -> q stays in registers.
    //     MFMA(A=wq_frag[l15->d, lg->k], B=h_frag[l15->row, lg->k]) ->
    //     lane holds q[row=l15][d = lg*4 + r].  Rebuild scores-A-frag via shuffles.
    bf16x8 aq[4];
    {
        const unsigned short* wb = wpk + OQ + wave * 2048;   // head = wave
        #pragma unroll
        for (int nt = 0; nt < 4; ++nt) {
            f32x4 cq = {0.f, 0.f, 0.f, 0.f};
            #pragma unroll
            for (int kt = 0; kt < 4; ++kt) {
                bf16x8 wqf = *(const bf16x8*)&wb[(kt * 64 + lane) * 8];
                bf16x8 hb  = *(const bf16x8*)&A[(nt * 16 + l15) * RLD + kt * 32 + lg * 8];
                cq = MFMA16(wqf, hb, cq);
            }
            unsigned int u0 = f2bf2u(cq[0], cq[1]);
            unsigned int u1 = f2bf2u(cq[2], cq[3]);
            // target lane (l15, lg<2) wants d = 8*lg..8*lg+7 for q-row l15:
            // gather from source lanes l15+32*lg (d=8lg..+3) and +16 (d=8lg+4..7)
            int s0 = l15 + 32 * lg;
            unsigned int a0 = __shfl((int)u0, s0);
            unsigned int a1 = __shfl((int)u1, s0);
            unsigned int a2 = __shfl((int)u0, s0 + 16);
            unsigned int a3 = __shfl((int)u1, s0 + 16);
            aq[nt] = (lane < 32) ? mk_bf16x8(a0, a1, a2, a3) : mk_bf16x8(0, 0, 0, 0);
        }
    }
    // (b) k (waves 0-3) / v (waves 4-7), row tile = wave&3, all 8 head-tiles
    {
        const int sec = wave >> 2;
        const int rtt = wave & 3;
        const int rw0 = rtt * 16 + lg * 4;
        const unsigned short* wb = wpk + ((sec == 0) ? OKk : OV);
        bf16x8 la[4];
        #pragma unroll
        for (int kt = 0; kt < 4; ++kt)
            la[kt] = *(const bf16x8*)&A[(rtt * 16 + l15) * RLD + kt * 32 + lg * 8];
        #pragma unroll 2
        for (int nt = 0; nt < 8; ++nt) {
            f32x4 c = {0.f, 0.f, 0.f, 0.f};
            #pragma unroll
            for (int kt = 0; kt < 4; ++kt) {
                bf16x8 b = *(const bf16x8*)&wb[((nt * 4 + kt) * 64 + lane) * 8];
                c = MFMA16(la[kt], b, c);
            }
            unsigned int u01 = f2bf2u(c[0], c[1]);
            unsigned int u23 = f2bf2u(c[2], c[3]);
            if (sec == 0) {
                int o = rw0 * RLD + nt * 16 + l15;
                Ck[o]           = (unsigned short)u01;
                Ck[o + RLD]     = (unsigned short)(u01 >> 16);
                Ck[o + 2 * RLD] = (unsigned short)u23;
                Ck[o + 3 * RLD] = (unsigned short)(u23 >> 16);
            } else {   // vT: rows adjacent -> one b64 store
                *(uint2*)&Vv[(nt * 16 + l15) * VLD + rw0] = make_uint2(u01, u23);
            }
        }
    }
    __syncthreads();

    // ---------------- attention: wave = head ----------------
    {
        unsigned short* pw = A + wave * 16 * VLD;   // P tile [16][64] (h dead)
        const int hcol = wave * 16;
        f32x4 ocs[4];
        bf16x8 zf = {0, 0, 0, 0, 0, 0, 0, 0};

        #pragma unroll    // FULL unroll: aq[mt]/ocs[mt] static, causal masks static
        for (int mt = 0; mt < 4; ++mt) {
            f32x4 sfr[4];
            #pragma unroll
            for (int st = 0; st < 4; ++st) sfr[st] = (f32x4){0.f, 0.f, 0.f, 0.f};
            #pragma unroll
            for (int st = 0; st < 4; ++st) {
                if (st <= mt) {
                    bf16x8 bk = zf;
                    if (lane < 32)
                        bk = *(const bf16x8*)&Ck[(st * 16 + l15) * RLD + hcol + lg * 8];
                    sfr[st] = MFMA16(aq[mt], bk, sfr[st]);
                }
            }
            float inv4[4];
            #pragma unroll
            for (int r = 0; r < 4; ++r) {
                float sv[4], e[4];
                float mx = -3.0e38f;
                #pragma unroll
                for (int st = 0; st < 4; ++st) {
                    if (st <= mt) {
                        float s = sfr[st][r];
                        if (st == mt) s = (l15 <= lg * 4 + r) ? s : -3.0e38f;
                        sv[st] = s;
                        mx = fmaxf(mx, s);
                    }
                }
                #pragma unroll
                for (int off = 1; off < 16; off <<= 1) mx = fmaxf(mx, __shfl_xor(mx, off));
                float sum = 0.f;
                #pragma unroll
                for (int st = 0; st < 4; ++st) {
                    if (st <= mt) { e[st] = __expf(sv[st] - mx); sum += e[st]; }
                }
                int ro = (lg * 4 + r) * VLD + l15;
                #pragma unroll
                for (int st = 0; st < 4; st += 2) {
                    if (st + 1 <= mt) {
                        unsigned int u = f2bf2u(e[st], e[st + 1]);
                        pw[ro + st * 16]       = (unsigned short)u;
                        pw[ro + (st + 1) * 16] = (unsigned short)(u >> 16);
                    } else if (st <= mt) {
                        pw[ro + st * 16]       = f2bf(e[st]);
                        pw[ro + (st + 1) * 16] = 0;
                    }
                }
                #pragma unroll
                for (int off = 1; off < 16; off <<= 1) sum += __shfl_xor(sum, off);
                inv4[r] = __builtin_amdgcn_rcpf(sum);
            }
            f32x4 oc = {0.f, 0.f, 0.f, 0.f};
            #pragma unroll
            for (int kt = 0; kt < 2; ++kt) {
                if (kt <= (mt >> 1)) {
                    bf16x8 ap = *(const bf16x8*)&pw[l15 * VLD + kt * 32 + lg * 8];
                    bf16x8 bv = *(const bf16x8*)&Vv[(hcol + l15) * VLD + kt * 32 + lg * 8];
                    oc = MFMA16(ap, bv, oc);
                }
            }
            #pragma unroll
            for (int r = 0; r < 4; ++r) oc[r] *= inv4[r];
            ocs[mt] = oc;
        }
        __syncthreads();   // all waves done reading Ck(k) and Vv(vT)
        #pragma unroll
        for (int mt = 0; mt < 4; ++mt) {   // attn concat -> Ck (k dead)
            unsigned int u01 = f2bf2u(ocs[mt][0], ocs[mt][1]);
            unsigned int u23 = f2bf2u(ocs[mt][2], ocs[mt][3]);
            int o = (mt * 16 + lg * 4) * RLD + hcol + l15;
            Ck[o]           = (unsigned short)u01;
            Ck[o + RLD]     = (unsigned short)(u01 >> 16);
            Ck[o + 2 * RLD] = (unsigned short)u23;
            Ck[o + 3 * RLD] = (unsigned short)(u23 >> 16);
        }
    }
    __syncthreads();

    // ---------------- proj + residual: x2 = x + attn @ Wp + bp -> Vv ----------------
    {
        bf16x8 pa[4];
        #pragma unroll
        for (int kt = 0; kt < 4; ++kt)
            pa[kt] = *(const bf16x8*)&Ck[(rt * 16 + l15) * RLD + kt * 32 + lg * 8];
        #pragma unroll
        for (int ntl = 0; ntl < 4; ++ntl) {
            int nt = cg * 4 + ntl;
            f32x4 c = {0.f, 0.f, 0.f, 0.f};
            #pragma unroll
            for (int kt = 0; kt < 4; ++kt) {
                bf16x8 b = *(const bf16x8*)&wpk[OP + ((nt * 4 + kt) * 64 + lane) * 8];
                c = MFMA16(pa[kt], b, c);
            }
            int col = nt * 16 + l15;
            float bpv = bp[col];
            unsigned int u01 = f2bf2u(xb[(row0 + 0) * CC + col] + c[0] + bpv,
                                      xb[(row0 + 1) * CC + col] + c[1] + bpv);
            unsigned int u23 = f2bf2u(xb[(row0 + 2) * CC + col] + c[2] + bpv,
                                      xb[(row0 + 3) * CC + col] + c[3] + bpv);
            int o = row0 * RLD + col;        // x2 into Vv (vT dead)
            Vv[o]           = (unsigned short)u01;
            Vv[o + RLD]     = (unsigned short)(u01 >> 16);
            Vv[o + 2 * RLD] = (unsigned short)u23;
            Vv[o + 3 * RLD] = (unsigned short)(u23 >> 16);
        }
    }
    __syncthreads();

    // ---------------- LN2: Vv(x2) -> A(h2); one-pass form ----------------
    {
        float ga = g2[lane], gb = g2[lane + 64], ba = be2[lane], bb = be2[lane + 64];
        #pragma unroll 2
        for (int r = wave * 8; r < wave * 8 + 8; ++r) {
            float v0 = bf2f(Vv[r * RLD + lane]), v1 = bf2f(Vv[r * RLD + lane + 64]);
            float s = v0 + v1;
            float q = fmaf(v0, v0, v1 * v1);
            #pragma unroll
            for (int off = 32; off; off >>= 1) {
                s += __shfl_xor(s, off);
                q += __shfl_xor(q, off);
            }
            float mean = s * (1.0f / CC);
            float var  = fmaf(-mean, mean, q * (1.0f / CC));
            float rstd = __builtin_amdgcn_rsqf(var + 1e-5f);
            float d0 = v0 - mean, d1 = v1 - mean;
            unsigned int u = f2bf2u(fmaf(ga, d0 * rstd, ba), fmaf(gb, d1 * rstd, bb));
            A[r * RLD + lane]      = (unsigned short)u;
            A[r * RLD + lane + 64] = (unsigned short)(u >> 16);
        }
    }
    __syncthreads();

    // ---------------- FF: out = x2 + gelu(h2@W1+b1)@W2 + b2 ----------------
    // f1 ping-pongs between Ck (even jc) and A (odd jc): one barrier per jc.
    {
        bf16x8 ha[4];
        #pragma unroll
        for (int kt = 0; kt < 4; ++kt)
            ha[kt] = *(const bf16x8*)&A[(rt * 16 + l15) * RLD + kt * 32 + lg * 8];
        f32x4 facc[4];
        #pragma unroll
        for (int n = 0; n < 4; ++n) facc[n] = (f32x4){0.f, 0.f, 0.f, 0.f};

        #pragma unroll 1
        for (int jc = 0; jc < 4; ++jc) {
            unsigned short* f1 = (jc & 1) ? A : Ck;
            #pragma unroll 2
            for (int ntl = 0; ntl < 4; ++ntl) {
                int ntg = jc * 8 + cg * 4 + ntl;
                f32x4 c = {0.f, 0.f, 0.f, 0.f};
                #pragma unroll
                for (int kt = 0; kt < 4; ++kt) {
                    bf16x8 b = *(const bf16x8*)&wpk[O1 + ((ntg * 4 + kt) * 64 + lane) * 8];
                    c = MFMA16(ha[kt], b, c);
                }
                float b1v = b1[ntg * 16 + l15];
                unsigned int u01 = f2bf2u(gelu_fast(c[0] + b1v), gelu_fast(c[1] + b1v));
                unsigned int u23 = f2bf2u(gelu_fast(c[2] + b1v), gelu_fast(c[3] + b1v));
                int o = row0 * RLD + (cg * 4 + ntl) * 16 + l15;
                f1[o]           = (unsigned short)u01;
                f1[o + RLD]     = (unsigned short)(u01 >> 16);
                f1[o + 2 * RLD] = (unsigned short)u23;
                f1[o + 3 * RLD] = (unsigned short)(u23 >> 16);
            }
            __syncthreads();
            #pragma unroll 2
            for (int kt = 0; kt < 4; ++kt) {
                int ktg = jc * 4 + kt;
                bf16x8 a0 = *(const bf16x8*)&f1[(rt * 16 + l15) * RLD + kt * 32 + lg * 8];
                #pragma unroll
                for (int ntl = 0; ntl < 4; ++ntl) {
                    int nt = cg * 4 + ntl;
                    bf16x8 b = *(const bf16x8*)&wpk[O2 + ((nt * 16 + ktg) * 64 + lane) * 8];
                    facc[ntl] = MFMA16(a0, b, facc[ntl]);
                }
            }
            // next FF1 writes the OTHER buffer; safe without trailing barrier
        }

        // epilogue: out = x2(Vv) + ff + b2
        #pragma unroll
        for (int ntl = 0; ntl < 4; ++ntl) {
            int col = (cg * 4 + ntl) * 16 + l15;
            float b2v = b2[col];
            #pragma unroll
            for (int r = 0; r < 4; ++r)
                ob[(row0 + r) * CC + col] =
                    bf2f(Vv[(row0 + r) * RLD + col]) + facc[ntl][r] + b2v;
        }
    }
}

extern "C" void kernel_launch(void* const* d_in, const int* in_sizes, int n_in,
                              void* d_out, int out_size, void* d_ws, size_t ws_size,
                              hipStream_t stream) {
    (void)n_in; (void)out_size; (void)ws_size;
    const float* x   = (const float*)d_in[0];
    const float* wq  = (const float*)d_in[1];
    const float* wk  = (const float*)d_in[2];
    const float* wv  = (const float*)d_in[3];
    const float* wp  = (const float*)d_in[4];
    const float* bp  = (const float*)d_in[5];
    const float* b1  = (const float*)d_in[7];
    const float* w1  = (const float*)d_in[6];
    const float* w2  = (const float*)d_in[8];
    const float* b2  = (const float*)d_in[9];
    const float* g1  = (const float*)d_in[10];
    const float* be1 = (const float*)d_in[11];
    const float* g2  = (const float*)d_in[12];
    const float* be2 = (const float*)d_in[13];

    unsigned short* ws16 = (unsigned short*)d_ws;
    pack_w<<<64,  256, 0, stream>>>(wq, ws16 + OQ,  128, 128, 1, 0.25f);  // HD^-0.5 folded
    pack_w<<<64,  256, 0, stream>>>(wk, ws16 + OKk, 128, 128, 1, 1.0f);
    pack_w<<<64,  256, 0, stream>>>(wv, ws16 + OV,  128, 128, 1, 1.0f);
    pack_w<<<64,  256, 0, stream>>>(wp, ws16 + OP,  128, 128, 0, 1.0f);
    pack_w<<<256, 256, 0, stream>>>(w1, ws16 + O1,  128, 512, 0, 1.0f);
    pack_w<<<256, 256, 0, stream>>>(w2, ws16 + O2,  512, 128, 0, 1.0f);

    int nblk = in_sizes[0] / (64 * CC);   // one block per batch element
    block_fused<<<dim3(nblk), dim3(512), 0, stream>>>(
        x, ws16, bp, b1, b2, g1, be1, g2, be2, (float*)d_out);
}

// Round 9
// 224.808 us; speedup vs baseline: 1.0160x; 1.0160x over previous
//
#include <hip/hip_runtime.h>
#include <hip/hip_bf16.h>
#include <math.h>

#define CC  128
#define RLD 136            // halves stride for [64][128] bf16 LDS tiles (272B)

typedef __attribute__((ext_vector_type(8))) short bf16x8;
typedef __attribute__((ext_vector_type(4))) float f32x4;

#define MFMA16(a, b, c) __builtin_amdgcn_mfma_f32_16x16x32_bf16((a), (b), (c), 0, 0, 0)

__device__ __forceinline__ unsigned short f2bf(float f) {
    unsigned int u = __float_as_uint(f);
    u += 0x7FFFu + ((u >> 16) & 1u);
    return (unsigned short)(u >> 16);
}
__device__ __forceinline__ float bf2f(unsigned short h) {
    return __uint_as_float(((unsigned int)h) << 16);
}
// pair convert -> v_cvt_pk_bf16_f32
__device__ __forceinline__ unsigned int f2bf2u(float lo, float hi) {
    __hip_bfloat162 h = __float22bfloat162_rn(make_float2(lo, hi));
    union { __hip_bfloat162 h2; unsigned int u; } cv; cv.h2 = h;
    return cv.u;
}
__device__ __forceinline__ bf16x8 mk_bf16x8(unsigned int a0, unsigned int a1,
                                            unsigned int a2, unsigned int a3) {
    union { uint4 u; bf16x8 b; } cv;
    cv.u = make_uint4(a0, a1, a2, a3);
    return cv.b;
}
// branch-free gelu: Phi via Abramowitz-Stegun 26.2.17 (|err| < 7.5e-8)
__device__ __forceinline__ float gelu_fast(float v) {
    float ax  = fabsf(v);
    float t   = __builtin_amdgcn_rcpf(fmaf(0.2316419f, ax, 1.0f));
    float phi = 0.39894228f * __expf(-0.5f * ax * ax);
    float p   = t * fmaf(t, fmaf(t, fmaf(t, fmaf(t, 1.330274429f, -1.821255978f),
                                   1.781477937f), -0.356563782f), 0.319381530f);
    float cpos = fmaf(-phi, p, 1.0f);          // Phi(|v|)
    float c    = (v >= 0.f) ? cpos : 1.0f - cpos;
    return v * c;
}

// ---- weight pre-pack: fragment-major bf16 (scale folded in) ----
__global__ void pack_w(const float* __restrict__ src, unsigned short* __restrict__ dst,
                       int K, int N, int mode, float scale) {
    int i = blockIdx.x * 256 + threadIdx.x;
    if (i >= K * N) return;
    int j   = i & 7;
    int l   = (i >> 3) & 63;
    int tkt = i >> 9;
    int KT  = K >> 5;
    int nt  = tkt / KT;
    int kt  = tkt - nt * KT;
    int k   = kt * 32 + (l >> 4) * 8 + j;
    int n   = nt * 16 + (l & 15);
    float v = (mode == 0) ? src[k * N + n]
                          : src[(n >> 4) * (K * 16) + k * 16 + (n & 15)];
    dst[i] = f2bf(v * scale);
}

// packed-weight half offsets in d_ws
#define OQ  0
#define OKk 16384
#define OV  32768
#define OP  49152
#define O1  65536
#define O2  131072

// One block = 1 batch element (64 rows). 512 threads = 8 waves.
// 3 LDS buffers x 8704 halves = 52,224 B -> 3 blocks/CU (6 waves/SIMD).
__global__ __launch_bounds__(512, 6) void block_fused(
    const float* __restrict__ x,
    const unsigned short* __restrict__ wpk,
    const float* __restrict__ bp,
    const float* __restrict__ b1, const float* __restrict__ b2,
    const float* __restrict__ g1, const float* __restrict__ be1,
    const float* __restrict__ g2, const float* __restrict__ be2,
    float* __restrict__ out)
{
    __shared__ __align__(16) unsigned short A [8704];  // h -> P tiles(swz) -> h2 -> f1(odd)
    __shared__ __align__(16) unsigned short Ck[8704];  // k -> attn concat -> f1(even)
    __shared__ __align__(16) unsigned short Vv[8704];  // vT(swz) -> x2

    const int tid  = threadIdx.x;
    const int lane = tid & 63;
    const int wave = tid >> 6;
    const int l15  = lane & 15;
    const int lg   = lane >> 4;
    const int l7   = l15 & 7;

    const float* xb = x   + (size_t)blockIdx.x * (64 * CC);
    float*       ob = out + (size_t)blockIdx.x * (64 * CC);

    // ---------------- LN1: x -> A (h, bf16); one-pass E[x^2] form ----------------
    {
        float ga = g1[lane], gb = g1[lane + 64], ba = be1[lane], bb = be1[lane + 64];
        #pragma unroll 2
        for (int r = wave * 8; r < wave * 8 + 8; ++r) {
            float v0 = xb[r * CC + lane], v1 = xb[r * CC + lane + 64];
            float s = v0 + v1;
            float q = fmaf(v0, v0, v1 * v1);
            #pragma unroll
            for (int off = 32; off; off >>= 1) {
                s += __shfl_xor(s, off);
                q += __shfl_xor(q, off);
            }
            float mean = s * (1.0f / CC);
            float var  = fmaf(-mean, mean, q * (1.0f / CC));
            float rstd = __builtin_amdgcn_rsqf(var + 1e-5f);
            float d0 = v0 - mean, d1 = v1 - mean;
            unsigned int u = f2bf2u(fmaf(ga, d0 * rstd, ba), fmaf(gb, d1 * rstd, bb));
            A[r * RLD + lane]      = (unsigned short)u;
            A[r * RLD + lane + 64] = (unsigned short)(u >> 16);
        }
    }
    __syncthreads();

    const int rt  = wave >> 1;          // GEMM-phase row tile (proj/FF)
    const int cg  = wave & 1;           // GEMM-phase column group
    const int row0 = rt * 16 + lg * 4;

    // ---------------- QKV ----------------
    // (a) q^T for THIS wave's head -> q in registers (aq frags for scores MFMA)
    bf16x8 aq[4];
    {
        const unsigned short* wb = wpk + OQ + wave * 2048;   // head = wave
        #pragma unroll
        for (int nt = 0; nt < 4; ++nt) {
            f32x4 cq = {0.f, 0.f, 0.f, 0.f};
            #pragma unroll
            for (int kt = 0; kt < 4; ++kt) {
                bf16x8 wqf = *(const bf16x8*)&wb[(kt * 64 + lane) * 8];
                bf16x8 hb  = *(const bf16x8*)&A[(nt * 16 + l15) * RLD + kt * 32 + lg * 8];
                cq = MFMA16(wqf, hb, cq);
            }
            unsigned int u0 = f2bf2u(cq[0], cq[1]);
            unsigned int u1 = f2bf2u(cq[2], cq[3]);
            int s0 = l15 + 32 * lg;
            unsigned int a0 = __shfl((int)u0, s0);
            unsigned int a1 = __shfl((int)u1, s0);
            unsigned int a2 = __shfl((int)u0, s0 + 16);
            unsigned int a3 = __shfl((int)u1, s0 + 16);
            aq[nt] = (lane < 32) ? mk_bf16x8(a0, a1, a2, a3) : mk_bf16x8(0, 0, 0, 0);
        }
    }
    // (b) k (waves 0-3) / v (waves 4-7), row tile = wave&3, all 8 head-tiles
    {
        const int sec = wave >> 2;
        const int rtt = wave & 3;
        const int rw0 = rtt * 16 + lg * 4;
        const unsigned short* wb = wpk + ((sec == 0) ? OKk : OV);
        bf16x8 la[4];
        #pragma unroll
        for (int kt = 0; kt < 4; ++kt)
            la[kt] = *(const bf16x8*)&A[(rtt * 16 + l15) * RLD + kt * 32 + lg * 8];
        #pragma unroll 2
        for (int nt = 0; nt < 8; ++nt) {
            f32x4 c = {0.f, 0.f, 0.f, 0.f};
            #pragma unroll
            for (int kt = 0; kt < 4; ++kt) {
                bf16x8 b = *(const bf16x8*)&wb[((nt * 4 + kt) * 64 + lane) * 8];
                c = MFMA16(la[kt], b, c);
            }
            unsigned int u01 = f2bf2u(c[0], c[1]);
            unsigned int u23 = f2bf2u(c[2], c[3]);
            if (sec == 0) {
                int o = rw0 * RLD + nt * 16 + l15;
                Ck[o]           = (unsigned short)u01;
                Ck[o + RLD]     = (unsigned short)(u01 >> 16);
                Ck[o + 2 * RLD] = (unsigned short)u23;
                Ck[o + 3 * RLD] = (unsigned short)(u23 >> 16);
            } else {
                // vT swizzled [128][64]: halves = row*64 + ((col16 ^ (row&7))<<3) + (col&7)
                // row = nt*16+l15 (row&7 = l7), cols rw0..rw0+3 (col16 = rw0>>3, col&7 = rw0&7)
                int vo = (nt * 16 + l15) * 64 + (((rw0 >> 3) ^ l7) << 3) + (rw0 & 7);
                *(uint2*)&Vv[vo] = make_uint2(u01, u23);
            }
        }
    }

    // prefetch proj's residual x (hide latency under attention); static indices
    float xpre[16];
    #pragma unroll
    for (int ntl = 0; ntl < 4; ++ntl) {
        int col = (cg * 4 + ntl) * 16 + l15;
        #pragma unroll
        for (int r = 0; r < 4; ++r)
            xpre[ntl * 4 + r] = xb[(row0 + r) * CC + col];
    }
    __syncthreads();

    // ---------------- attention: wave = head ----------------
    {
        unsigned short* pw = A + wave * 1024;   // P tile [16][64] swizzled (h dead)
        const int hcol = wave * 16;
        f32x4 ocs[4];
        bf16x8 zf = {0, 0, 0, 0, 0, 0, 0, 0};

        #pragma unroll    // FULL unroll: aq[mt]/ocs[mt] static, causal masks static
        for (int mt = 0; mt < 4; ++mt) {
            f32x4 sfr[4];
            #pragma unroll
            for (int st = 0; st < 4; ++st) sfr[st] = (f32x4){0.f, 0.f, 0.f, 0.f};
            #pragma unroll
            for (int st = 0; st < 4; ++st) {
                if (st <= mt) {
                    bf16x8 bk = zf;
                    if (lane < 32)
                        bk = *(const bf16x8*)&Ck[(st * 16 + l15) * RLD + hcol + lg * 8];
                    sfr[st] = MFMA16(aq[mt], bk, sfr[st]);
                }
            }
            float inv4[4];
            #pragma unroll
            for (int r = 0; r < 4; ++r) {
                float sv[4], e[4];
                float mx = -3.0e38f;
                #pragma unroll
                for (int st = 0; st < 4; ++st) {
                    if (st <= mt) {
                        float s = sfr[st][r];
                        if (st == mt) s = (l15 <= lg * 4 + r) ? s : -3.0e38f;
                        sv[st] = s;
                        mx = fmaxf(mx, s);
                    }
                }
                #pragma unroll
                for (int off = 1; off < 16; off <<= 1) mx = fmaxf(mx, __shfl_xor(mx, off));
                float sum = 0.f;
                #pragma unroll
                for (int st = 0; st < 4; ++st) {
                    if (st <= mt) { e[st] = __expf(sv[st] - mx); sum += e[st]; }
                }
                // P writes (swizzled): row pr, col st*16+l15 -> col16 = 2st + (l15>>3)
                int pr    = lg * 4 + r;
                int pbase = pr * 64 + l7;
                int psw   = pr & 7;
                int phi   = l15 >> 3;
                #pragma unroll
                for (int st = 0; st < 4; st += 2) {
                    if (st + 1 <= mt) {
                        unsigned int u = f2bf2u(e[st], e[st + 1]);
                        pw[pbase + (((2 * st + phi) ^ psw) << 3)]       = (unsigned short)u;
                        pw[pbase + (((2 * (st + 1) + phi) ^ psw) << 3)] = (unsigned short)(u >> 16);
                    } else if (st <= mt) {
                        pw[pbase + (((2 * st + phi) ^ psw) << 3)]       = f2bf(e[st]);
                        pw[pbase + (((2 * (st + 1) + phi) ^ psw) << 3)] = 0;
                    }
                }
                #pragma unroll
                for (int off = 1; off < 16; off <<= 1) sum += __shfl_xor(sum, off);
                inv4[r] = __builtin_amdgcn_rcpf(sum);
            }
            f32x4 oc = {0.f, 0.f, 0.f, 0.f};
            #pragma unroll
            for (int kt = 0; kt < 2; ++kt) {
                if (kt <= (mt >> 1)) {
                    // swizzled reads: row l15 / hcol+l15, col16 = kt*4+lg
                    bf16x8 ap = *(const bf16x8*)&pw[l15 * 64 + (((kt * 4 + lg) ^ l7) << 3)];
                    bf16x8 bv = *(const bf16x8*)&Vv[(hcol + l15) * 64 + (((kt * 4 + lg) ^ l7) << 3)];
                    oc = MFMA16(ap, bv, oc);
                }
            }
            #pragma unroll
            for (int r = 0; r < 4; ++r) oc[r] *= inv4[r];
            ocs[mt] = oc;
        }
        __syncthreads();   // all waves done reading Ck(k) and Vv(vT)
        #pragma unroll
        for (int mt = 0; mt < 4; ++mt) {   // attn concat -> Ck (k dead)
            unsigned int u01 = f2bf2u(ocs[mt][0], ocs[mt][1]);
            unsigned int u23 = f2bf2u(ocs[mt][2], ocs[mt][3]);
            int o = (mt * 16 + lg * 4) * RLD + hcol + l15;
            Ck[o]           = (unsigned short)u01;
            Ck[o + RLD]     = (unsigned short)(u01 >> 16);
            Ck[o + 2 * RLD] = (unsigned short)u23;
            Ck[o + 3 * RLD] = (unsigned short)(u23 >> 16);
        }
    }
    __syncthreads();

    // ---------------- proj + residual: x2 = x + attn @ Wp + bp -> Vv(RLD) ----------------
    {
        bf16x8 pa[4];
        #pragma unroll
        for (int kt = 0; kt < 4; ++kt)
            pa[kt] = *(const bf16x8*)&Ck[(rt * 16 + l15) * RLD + kt * 32 + lg * 8];
        #pragma unroll
        for (int ntl = 0; ntl < 4; ++ntl) {
            int nt = cg * 4 + ntl;
            f32x4 c = {0.f, 0.f, 0.f, 0.f};
            #pragma unroll
            for (int kt = 0; kt < 4; ++kt) {
                bf16x8 b = *(const bf16x8*)&wpk[OP + ((nt * 4 + kt) * 64 + lane) * 8];
                c = MFMA16(pa[kt], b, c);
            }
            int col = nt * 16 + l15;
            float bpv = bp[col];
            unsigned int u01 = f2bf2u(xpre[ntl * 4 + 0] + c[0] + bpv,
                                      xpre[ntl * 4 + 1] + c[1] + bpv);
            unsigned int u23 = f2bf2u(xpre[ntl * 4 + 2] + c[2] + bpv,
                                      xpre[ntl * 4 + 3] + c[3] + bpv);
            int o = row0 * RLD + col;        // x2 into Vv (vT dead)
            Vv[o]           = (unsigned short)u01;
            Vv[o + RLD]     = (unsigned short)(u01 >> 16);
            Vv[o + 2 * RLD] = (unsigned short)u23;
            Vv[o + 3 * RLD] = (unsigned short)(u23 >> 16);
        }
    }
    __syncthreads();

    // ---------------- LN2: Vv(x2) -> A(h2); one-pass form ----------------
    {
        float ga = g2[lane], gb = g2[lane + 64], ba = be2[lane], bb = be2[lane + 64];
        #pragma unroll 2
        for (int r = wave * 8; r < wave * 8 + 8; ++r) {
            float v0 = bf2f(Vv[r * RLD + lane]), v1 = bf2f(Vv[r * RLD + lane + 64]);
            float s = v0 + v1;
            float q = fmaf(v0, v0, v1 * v1);
            #pragma unroll
            for (int off = 32; off; off >>= 1) {
                s += __shfl_xor(s, off);
                q += __shfl_xor(q, off);
            }
            float mean = s * (1.0f / CC);
            float var  = fmaf(-mean, mean, q * (1.0f / CC));
            float rstd = __builtin_amdgcn_rsqf(var + 1e-5f);
            float d0 = v0 - mean, d1 = v1 - mean;
            unsigned int u = f2bf2u(fmaf(ga, d0 * rstd, ba), fmaf(gb, d1 * rstd, bb));
            A[r * RLD + lane]      = (unsigned short)u;
            A[r * RLD + lane + 64] = (unsigned short)(u >> 16);
        }
    }
    __syncthreads();

    // ---------------- FF: out = x2 + gelu(h2@W1+b1)@W2 + b2 ----------------
    // f1 ping-pongs between Ck (even jc) and A (odd jc): one barrier per jc.
    {
        bf16x8 ha[4];
        #pragma unroll
        for (int kt = 0; kt < 4; ++kt)
            ha[kt] = *(const bf16x8*)&A[(rt * 16 + l15) * RLD + kt * 32 + lg * 8];
        f32x4 facc[4];
        #pragma unroll
        for (int n = 0; n < 4; ++n) facc[n] = (f32x4){0.f, 0.f, 0.f, 0.f};

        #pragma unroll 1
        for (int jc = 0; jc < 4; ++jc) {
            unsigned short* f1 = (jc & 1) ? A : Ck;
            #pragma unroll 2
            for (int ntl = 0; ntl < 4; ++ntl) {
                int ntg = jc * 8 + cg * 4 + ntl;
                f32x4 c = {0.f, 0.f, 0.f, 0.f};
                #pragma unroll
                for (int kt = 0; kt < 4; ++kt) {
                    bf16x8 b = *(const bf16x8*)&wpk[O1 + ((ntg * 4 + kt) * 64 + lane) * 8];
                    c = MFMA16(ha[kt], b, c);
                }
                float b1v = b1[ntg * 16 + l15];
                unsigned int u01 = f2bf2u(gelu_fast(c[0] + b1v), gelu_fast(c[1] + b1v));
                unsigned int u23 = f2bf2u(gelu_fast(c[2] + b1v), gelu_fast(c[3] + b1v));
                int o = row0 * RLD + (cg * 4 + ntl) * 16 + l15;
                f1[o]           = (unsigned short)u01;
                f1[o + RLD]     = (unsigned short)(u01 >> 16);
                f1[o + 2 * RLD] = (unsigned short)u23;
                f1[o + 3 * RLD] = (unsigned short)(u23 >> 16);
            }
            __syncthreads();
            #pragma unroll 2
            for (int kt = 0; kt < 4; ++kt) {
                int ktg = jc * 4 + kt;
                bf16x8 a0 = *(const bf16x8*)&f1[(rt * 16 + l15) * RLD + kt * 32 + lg * 8];
                #pragma unroll
                for (int ntl = 0; ntl < 4; ++ntl) {
                    int nt = cg * 4 + ntl;
                    bf16x8 b = *(const bf16x8*)&wpk[O2 + ((nt * 16 + ktg) * 64 + lane) * 8];
                    facc[ntl] = MFMA16(a0, b, facc[ntl]);
                }
            }
            // next FF1 writes the OTHER buffer; safe without trailing barrier
        }

        // epilogue: out = x2(Vv) + ff + b2
        #pragma unroll
        for (int ntl = 0; ntl < 4; ++ntl) {
            int col = (cg * 4 + ntl) * 16 + l15;
            float b2v = b2[col];
            #pragma unroll
            for (int r = 0; r < 4; ++r)
                ob[(row0 + r) * CC + col] =
                    bf2f(Vv[(row0 + r) * RLD + col]) + facc[ntl][r] + b2v;
        }
    }
}

extern "C" void kernel_launch(void* const* d_in, const int* in_sizes, int n_in,
                              void* d_out, int out_size, void* d_ws, size_t ws_size,
                              hipStream_t stream) {
    (void)n_in; (void)out_size; (void)ws_size;
    const float* x   = (const float*)d_in[0];
    const float* wq  = (const float*)d_in[1];
    const float* wk  = (const float*)d_in[2];
    const float* wv  = (const float*)d_in[3];
    const float* wp  = (const float*)d_in[4];
    const float* bp  = (const float*)d_in[5];
    const float* w1  = (const float*)d_in[6];
    const float* b1  = (const float*)d_in[7];
    const float* w2  = (const float*)d_in[8];
    const float* b2  = (const float*)d_in[9];
    const float* g1  = (const float*)d_in[10];
    const float* be1 = (const float*)d_in[11];
    const float* g2  = (const float*)d_in[12];
    const float* be2 = (const float*)d_in[13];

    unsigned short* ws16 = (unsigned short*)d_ws;
    pack_w<<<64,  256, 0, stream>>>(wq, ws16 + OQ,  128, 128, 1, 0.25f);  // HD^-0.5 folded
    pack_w<<<64,  256, 0, stream>>>(wk, ws16 + OKk, 128, 128, 1, 1.0f);
    pack_w<<<64,  256, 0, stream>>>(wv, ws16 + OV,  128, 128, 1, 1.0f);
    pack_w<<<64,  256, 0, stream>>>(wp, ws16 + OP,  128, 128, 0, 1.0f);
    pack_w<<<256, 256, 0, stream>>>(w1, ws16 + O1,  128, 512, 0, 1.0f);
    pack_w<<<256, 256, 0, stream>>>(w2, ws16 + O2,  512, 128, 0, 1.0f);

    int nblk = in_sizes[0] / (64 * CC);   // one block per batch element
    block_fused<<<dim3(nblk), dim3(512), 0, stream>>>(
        x, ws16, bp, b1, b2, g1, be1, g2, be2, (float*)d_out);
}